// Round 9
// baseline (176.331 us; speedup 1.0000x reference)
//
#include <hip/hip_runtime.h>
#include <math.h>

#define B 4
#define S 2048
#define E 1024
#define H 64
#define BS (B*S)
#define LOG2E 1.44269504088896f
#define CINIT (-69.2493662f)   // -48 * log2(e): fixed softmax max in log2 domain

typedef float v4f __attribute__((ext_vector_type(4)));
typedef short v8s __attribute__((ext_vector_type(8)));
typedef unsigned short u16;
typedef u16 u16x8 __attribute__((ext_vector_type(8)));
typedef u16 u16x4 __attribute__((ext_vector_type(4)));

#define MFMA(a,b,c) __builtin_amdgcn_mfma_f32_16x16x32_bf16(a,b,c,0,0,0)

// Barrier WITHOUT the __syncthreads vmcnt(0) drain: both proj-loop
// hazards are DS-only (ds_read before overwrite / ds_write before read),
// so lgkmcnt(0)+s_barrier suffices; in-flight global loads survive.
#define BARRIER_L() do { \
    asm volatile("s_waitcnt lgkmcnt(0)" ::: "memory"); \
    __builtin_amdgcn_s_barrier(); \
} while (0)

// round-half-up fp32 -> bf16
__device__ inline u16 rh_bf16(float x){ return (u16)((__float_as_uint(x)+0x8000u)>>16); }

// ============================================================
// k0: W[E][H] fp32 -> FRAGMENT-MAJOR hi/lo bf16 planes:
//   WF elem offset = ((p*16+ec)*1024 + (nt*4+pl*2+b01)*64 + lane)*8
// so proj's B-fragments are single coalesced 16B/lane loads with a
// wave-uniform base (verified correct in an earlier passing round).
// p==0 (Wq) pre-scaled by log2(e) (scores land in log2 domain).
// ============================================================
__global__ __launch_bounds__(256) void wsetup_kernel(
    const float* __restrict__ Wq, const float* __restrict__ Wk,
    const float* __restrict__ Wv, u16* __restrict__ WF)
{
    __shared__ float wt[64][65];
    const int t  = threadIdx.x;
    const int p  = blockIdx.x >> 4;
    const int ec = blockIdx.x & 15, e0 = ec*64;
    const float* Wsrc = (p==0) ? Wq : (p==1 ? Wk : Wv);
    const float scale = (p==0) ? LOG2E : 1.0f;

    #pragma unroll
    for (int i=0;i<16;i++){
        int e_l = i*4 + (t>>6);
        wt[e_l][t&63] = Wsrc[(size_t)(e0+e_l)*H + (t&63)] * scale;
    }
    __syncthreads();

    // each thread emits 4 consecutive 8-u16 fragments (64 B, coalesced)
    u16* dst = WF + (((size_t)(p*16 + ec))*1024 + (size_t)t*4)*8;
    #pragma unroll
    for (int k=0;k<4;k++){
        const int c   = t*4 + k;
        const int l   = c & 63, b01 = (c>>6)&1, pl = (c>>7)&1, nt = c>>8;
        const int m   = l & 15, quad = l>>4;
        u16 o8[8];
        #pragma unroll
        for (int j=0;j<8;j++){
            float f = wt[b01*32 + quad*8 + j][nt*16 + m];
            unsigned u = __float_as_uint(f);
            if (pl==0) o8[j] = (u16)(u>>16);
            else       o8[j] = rh_bf16(f - __uint_as_float(u & 0xFFFF0000u));
        }
        *(u16x8*)(dst + (size_t)k*8) = *(u16x8*)&o8[0];
    }
}

// ============================================================
// k1: projections, MAX-STREAM layout: 1536 blocks x 128 thr (2 waves),
// 16 rows x 64 h per block, LDS ~7.5 KB -> 6 independent blocks/CU.
// x staged in LDS (coalesced, hi/lo convert); W read DIRECTLY from the
// fragment-major WF slab (L2-hot, one coalesced dwordx4 per fragment,
// never touches LDS). Distance-2 register ping-pong, compute-before-
// prefetch, lgkm-only barriers (global loads stay in flight).
// v projection (p==2) transposed in-block, written to vt[b][h][s].
// ============================================================
__global__ __launch_bounds__(128, 3) void proj_kernel(
    const float* __restrict__ query, const float* __restrict__ key_,
    const float* __restrict__ value,
    const u16* __restrict__ WF,
    const float* __restrict__ bq, const float* __restrict__ bk,
    const float* __restrict__ bv,
    u16* __restrict__ q_hi, u16* __restrict__ q_lo,
    u16* __restrict__ k_hi, u16* __restrict__ k_lo,
    u16* __restrict__ vt)
{
    __shared__ __align__(16) u16 xh[16][72], xl[16][72];  // x tile hi/lo
    __shared__ __align__(16) u16 vtile[64][24];           // epilogue only

    const int t  = threadIdx.x;              // 0..127
    const int p  = blockIdx.x >> 9;          // 0..2
    const int r0 = (blockIdx.x & 511) * 16;  // global row base (flat [BS])
    const float* xp = (p==0) ? query : (p==1 ? key_ : value);
    const int wv = t>>6, lane = t&63, m = lane&15, quad = lane>>4;
    // wv = h-half (both waves share the block's 16 A-rows)

    // x staging: thread -> row t>>3, cols (t&7)*8 (2 float4, coalesced)
    const int sxr = t>>3, sxc = (t&7)*8;
    const float* xb = xp + (size_t)(r0+sxr)*E + sxc;

    // W fragment base: wave-uniform except lane*8 (16B/lane, coalesced)
    const u16* wfb = WF + (size_t)p*131072 + (size_t)wv*4096 + (size_t)lane*8;
    // chunk ec: +ec*8192 ; n-tile i in half: +i*2048 ; frags {hi-b0,hi-b1,
    // lo-b0,lo-b1} at +0,+512,+1024,+1536

    v4f acc[2];
    acc[0] = (v4f){0.f,0.f,0.f,0.f};
    acc[1] = (v4f){0.f,0.f,0.f,0.f};

    float4 xA[2], xB[2];
    v8s    wA[8], wB[8];

#define LOADX(X, EC) {                                                         \
        const float* xa = xb + (EC)*64;                                        \
        X[0] = *(const float4*)(xa);                                           \
        X[1] = *(const float4*)(xa+4);                                         \
    }
#define LOADW(W, EC) {                                                         \
        const u16* wb = wfb + (size_t)(EC)*8192;                               \
        W[0] = *(const v8s*)(wb);          W[1] = *(const v8s*)(wb+512);       \
        W[2] = *(const v8s*)(wb+1024);     W[3] = *(const v8s*)(wb+1536);      \
        W[4] = *(const v8s*)(wb+2048);     W[5] = *(const v8s*)(wb+2560);      \
        W[6] = *(const v8s*)(wb+3072);     W[7] = *(const v8s*)(wb+3584);      \
    }
#define PHASE(EC, XC, WC, PREF)                                                \
    {                                                                          \
        BARRIER_L();   /* prev phase's xh readers done */                      \
        {                                                                      \
            float fv[8] = {XC[0].x,XC[0].y,XC[0].z,XC[0].w,                    \
                           XC[1].x,XC[1].y,XC[1].z,XC[1].w};                   \
            u16 ha[8], la[8];                                                  \
            _Pragma("unroll")                                                  \
            for (int j=0;j<8;j++){                                             \
                unsigned u = __float_as_uint(fv[j]);                           \
                ha[j] = (u16)(u>>16);                                          \
                la[j] = rh_bf16(fv[j] - __uint_as_float(u & 0xFFFF0000u));     \
            }                                                                  \
            *(u16x8*)&xh[sxr][sxc] = *(u16x8*)&ha[0];                          \
            *(u16x8*)&xl[sxr][sxc] = *(u16x8*)&la[0];                          \
        }                                                                      \
        BARRIER_L();   /* x tile visible */                                    \
        v8s ah0 = *(const v8s*)&xh[m][quad*8];                                 \
        v8s ah1 = *(const v8s*)&xh[m][32+quad*8];                              \
        v8s al0 = *(const v8s*)&xl[m][quad*8];                                 \
        v8s al1 = *(const v8s*)&xl[m][32+quad*8];                              \
        v4f d0 = acc[0];                                                       \
        d0 = MFMA(ah0,WC[0],d0); d0 = MFMA(ah1,WC[1],d0);                      \
        d0 = MFMA(al0,WC[0],d0); d0 = MFMA(al1,WC[1],d0);                      \
        d0 = MFMA(ah0,WC[2],d0); d0 = MFMA(ah1,WC[3],d0);                      \
        acc[0] = d0;                                                           \
        v4f d1 = acc[1];                                                       \
        d1 = MFMA(ah0,WC[4],d1); d1 = MFMA(ah1,WC[5],d1);                      \
        d1 = MFMA(al0,WC[4],d1); d1 = MFMA(al1,WC[5],d1);                      \
        d1 = MFMA(ah0,WC[6],d1); d1 = MFMA(ah1,WC[7],d1);                      \
        acc[1] = d1;                                                           \
        if (PREF){ LOADX(XC, (EC)+2); LOADW(WC, (EC)+2); }                     \
    }

    LOADX(xA, 0); LOADW(wA, 0);
    LOADX(xB, 1); LOADW(wB, 1);
    for (int ec2=0; ec2<16; ec2+=2){
        PHASE(ec2,   xA, wA, (ec2+2<16))
        PHASE(ec2+1, xB, wB, (ec2+3<16))
    }
#undef LOADX
#undef LOADW
#undef PHASE

    // ---- epilogue ----
    const float* bp = (p==0) ? bq : (p==1 ? bk : bv);
    if (p<2){
        const float bscale = (p==0) ? LOG2E : 1.0f;
        u16* dh = (p==0) ? q_hi : k_hi;
        u16* dl = (p==0) ? q_lo : k_lo;
        #pragma unroll
        for (int i=0;i<2;i++){
            const int hl = wv*32 + i*16 + m;
            const float bb = bp[hl]*bscale;
            #pragma unroll
            for (int r=0;r<4;r++){
                const int gr = r0 + quad*4 + r;   // D: row = quad*4+reg
                const float val = acc[i][r] + bb;
                unsigned u = __float_as_uint(val);
                u16 hi = (u16)(u>>16);
                float hif = __uint_as_float(u & 0xFFFF0000u);
                u16 lo = rh_bf16(val - hif);
                dh[(size_t)gr*H + hl] = hi;
                dl[(size_t)gr*H + hl] = lo;
            }
        }
    } else {
        // v: bf16 into LDS transposed, then store to vt[b][h][s]
        #pragma unroll
        for (int i=0;i<2;i++){
            const int hl = wv*32 + i*16 + m;
            const float bb = bp[hl];
            u16 vv[4];
            #pragma unroll
            for (int r=0;r<4;r++) vv[r] = rh_bf16(acc[i][r] + bb);
            *(u16x4*)&vtile[hl][quad*4] = *(u16x4*)&vv[0];
        }
        __syncthreads();
        const int h = t>>1, so = (t&1)*8;
        const int bidx = r0 >> 11, s0l = r0 & (S-1);
        u16* dst = vt + ((size_t)(bidx*H + h))*S + s0l + so;
        *(u16x8*)dst = *(const u16x8*)&vtile[h][so];
    }
}

// ============================================================
// k3: flash attention, fixed-max softmax (log2 domain), split-K.
// block = 256 thr (4 waves x 16 q-rows = 64 q-rows), TK=32/iter.
// (best-measured configuration, unchanged)
// ============================================================
__global__ __launch_bounds__(256, 4) void attn_kernel(
    const u16* __restrict__ qh_g, const u16* __restrict__ ql_g,
    const u16* __restrict__ kh_g, const u16* __restrict__ kl_g,
    const u16* __restrict__ vt_g,
    float* __restrict__ accw, float* __restrict__ lw, int ksplit)
{
    __shared__ __align__(16) u16 khe[2][16][72];   // [jj&1][jj>>1][h]
    __shared__ __align__(16) u16 kle[2][16][72];
    __shared__ __align__(16) u16 vtl[64][40];      // [h][jj]
    __shared__ __align__(16) u16 pl[4][16][40];    // per-wave P [row][jj]

    const int t = threadIdx.x;
    const int wv = t>>6, lane = t&63, m = lane&15, quad = lane>>4;
    const int bid = blockIdx.x;
    const int qb = bid / ksplit, chunk = bid % ksplit;
    const int b = qb >> 5, s0 = (qb & 31)*64;
    const int ck = S / ksplit;
    const int j0base = chunk * ck;
    const int iters = ck / 32;

    // persistent q fragments (hi c0/c1, lo c0/c1)
    const u16* qr = qh_g + (size_t)(b*S + s0 + wv*16 + m)*H + quad*8;
    const u16* qrl = ql_g + (size_t)(b*S + s0 + wv*16 + m)*H + quad*8;
    const v8s qh0 = *(const v8s*)(qr),  qh1 = *(const v8s*)(qr+32);
    const v8s ql0 = *(const v8s*)(qrl), ql1 = *(const v8s*)(qrl+32);

    v4f oacc[4];
    #pragma unroll
    for (int nt=0;nt<4;nt++) oacc[nt] = (v4f){0.f,0.f,0.f,0.f};
    float lp[4] = {0.f,0.f,0.f,0.f};
    const v4f cinit = (v4f){CINIT,CINIT,CINIT,CINIT};

    // staging coords
    const int sj = t>>3, sh8 = (t&7)*8;   // K tiles: 32 rows x 64 h
    const u16* khs = kh_g + (size_t)(b*S + j0base + sj)*H + sh8;
    const u16* kls = kl_g + (size_t)(b*S + j0base + sj)*H + sh8;
    u16* khd = &khe[sj&1][sj>>1][sh8];
    u16* kld = &kle[sj&1][sj>>1][sh8];
    const int vh = t>>2, vj8 = (t&3)*8;   // vt tile: 64 h x 32 jj
    const u16* vts = vt_g + (size_t)(b*H + vh)*S + j0base + vj8;
    u16* vtd = &vtl[vh][vj8];

    // ping-pong staging registers
    u16x8 khA, klA, vtA, khB, klB, vtB;
    khA = *(const u16x8*)khs;
    klA = *(const u16x8*)kls;
    vtA = *(const u16x8*)vts;

#define ATTN_ITER(IT, KHC, KLC, VTC, KHN, KLN, VTN, PREF)                      \
    {                                                                          \
        __syncthreads();                                                       \
        *(u16x8*)khd = KHC; *(u16x8*)kld = KLC; *(u16x8*)vtd = VTC;            \
        if (PREF){                                                             \
            KHN = *(const u16x8*)(khs + (size_t)((IT)+1)*32*H);                \
            KLN = *(const u16x8*)(kls + (size_t)((IT)+1)*32*H);                \
            VTN = *(const u16x8*)(vts + ((IT)+1)*32);                          \
        }                                                                      \
        __syncthreads();                                                       \
        /* QK^T: 2 D-tiles x 6 MFMAs (3-term hi/lo), C-init = -m_fix */        \
        v4f sc[2];                                                             \
        _Pragma("unroll")                                                      \
        for (int jt=0;jt<2;jt++){                                              \
            const u16* kr  = &khe[jt][m][quad*8];                              \
            const u16* krl = &kle[jt][m][quad*8];                              \
            v8s b0 = *(const v8s*)kr,  b1 = *(const v8s*)(kr+32);              \
            v8s c0 = *(const v8s*)krl, c1 = *(const v8s*)(krl+32);             \
            v4f d = cinit;                                                     \
            d = MFMA(qh0,b0,d); d = MFMA(qh1,b1,d);                            \
            d = MFMA(ql0,b0,d); d = MFMA(ql1,b1,d);                            \
            d = MFMA(qh0,c0,d); d = MFMA(qh1,c1,d);                            \
            sc[jt] = d;                                                        \
        }                                                                      \
        /* P = exp2(s'), accumulate l, pack bf16 pairs to wave-local LDS */    \
        _Pragma("unroll")                                                      \
        for (int r=0;r<4;r++){                                                 \
            float p0 = exp2f(sc[0][r]);   /* key j0 + 2m   */                  \
            float p1 = exp2f(sc[1][r]);   /* key j0 + 2m+1 */                  \
            lp[r] += p0 + p1;                                                  \
            unsigned pk = ((__float_as_uint(p0)+0x8000u)>>16)                  \
                        | ((__float_as_uint(p1)+0x8000u) & 0xFFFF0000u);       \
            *(unsigned*)&pl[wv][quad*4+r][2*m] = pk;                           \
        }                                                                      \
        /* no barrier: pl[wv] is wave-private, DS ops are in program order */  \
        v8s pa = *(const v8s*)&pl[wv][m][quad*8];                              \
        _Pragma("unroll")                                                      \
        for (int nt=0;nt<4;nt++){                                              \
            v8s vb = *(const v8s*)&vtl[nt*16+m][quad*8];                       \
            oacc[nt] = MFMA(pa, vb, oacc[nt]);                                 \
        }                                                                      \
    }

    for (int it=0; it<iters; it+=2){   // iters = 64/ksplit, always even
        ATTN_ITER(it,   khA,klA,vtA, khB,klB,vtB, true)
        ATTN_ITER(it+1, khB,klB,vtB, khA,klA,vtA, (it+2<iters))
    }
#undef ATTN_ITER

    // ---- epilogue: reduce l across 16 cols, write partials ----
    #pragma unroll
    for (int r=0;r<4;r++){
        float v = lp[r];
        v += __shfl_xor(v,1); v += __shfl_xor(v,2);
        v += __shfl_xor(v,4); v += __shfl_xor(v,8);
        lp[r] = v;
    }
    const int growb = b*S + s0 + wv*16;
    if (m==0){
        float4 lv; lv.x=lp[0]; lv.y=lp[1]; lv.z=lp[2]; lv.w=lp[3];
        *(float4*)(lw + (size_t)chunk*BS + growb + quad*4) = lv;
    }
    float* ab = accw + ((size_t)chunk*BS + growb)*H;
    #pragma unroll
    for (int nt=0;nt<4;nt++){
        #pragma unroll
        for (int r=0;r<4;r++)
            ab[(size_t)(quad*4+r)*H + nt*16 + m] = oacc[nt][r];
    }
}

// ============================================================
// k4: merge split-K partials: out = sum_c acc / sum_c l
// ============================================================
__global__ __launch_bounds__(256) void merge_kernel(
    const float* __restrict__ accw, const float* __restrict__ lw,
    float* __restrict__ out, int ksplit)
{
    const int idx = blockIdx.x*256 + threadIdx.x;
    const int row = idx >> 4, h4 = (idx & 15)*4;
    float4 a = {0.f,0.f,0.f,0.f};
    float ls = 0.f;
    for (int c=0;c<ksplit;c++){
        const float4 t4 = *(const float4*)(accw + ((size_t)c*BS + row)*H + h4);
        a.x+=t4.x; a.y+=t4.y; a.z+=t4.z; a.w+=t4.w;
        ls += lw[(size_t)c*BS + row];
    }
    const float inv = __builtin_amdgcn_rcpf(ls);
    float4 o; o.x=a.x*inv; o.y=a.y*inv; o.z=a.z*inv; o.w=a.w*inv;
    *(float4*)(out + (size_t)row*H + h4) = o;
}

// ============================================================
extern "C" void kernel_launch(void* const* d_in, const int* in_sizes, int n_in,
                              void* d_out, int out_size, void* d_ws, size_t ws_size,
                              hipStream_t stream) {
    const float* query = (const float*)d_in[0];
    const float* key_  = (const float*)d_in[1];
    const float* value = (const float*)d_in[2];
    const float* Wq    = (const float*)d_in[3];
    const float* bq    = (const float*)d_in[4];
    const float* Wk    = (const float*)d_in[5];
    const float* bk    = (const float*)d_in[6];
    const float* Wv    = (const float*)d_in[7];
    const float* bv    = (const float*)d_in[8];
    float* out = (float*)d_out;

    char* base = (char*)d_ws;
    size_t off = 0;
    u16* WF    = (u16*)(base + off); off += (size_t)3*16*1024*8*2;  // 768 KB
    u16* q_hi  = (u16*)(base + off); off += (size_t)BS*H*2;
    u16* q_lo  = (u16*)(base + off); off += (size_t)BS*H*2;
    u16* k_hi  = (u16*)(base + off); off += (size_t)BS*H*2;
    u16* k_lo  = (u16*)(base + off); off += (size_t)BS*H*2;
    u16* vt    = (u16*)(base + off); off += (size_t)BS*H*2;
    const size_t fixed = off;
    const size_t CH = (size_t)BS*H*4 + (size_t)BS*4;  // acc + l per chunk

    int K = 1;
    if      (ws_size >= fixed + 8*CH) K = 8;
    else if (ws_size >= fixed + 4*CH) K = 4;
    else if (ws_size >= fixed + 2*CH) K = 2;

    float* lw   = (float*)(base + fixed);
    float* accw = (float*)(base + fixed + (size_t)K*BS*4);

    wsetup_kernel<<<48, 256, 0, stream>>>(Wq, Wk, Wv, WF);
    proj_kernel<<<1536, 128, 0, stream>>>(query, key_, value, WF,
                                          bq, bk, bv, q_hi, q_lo, k_hi, k_lo, vt);
    attn_kernel<<<128*K, 256, 0, stream>>>(q_hi, q_lo, k_hi, k_lo, vt, accw, lw, K);
    merge_kernel<<<512, 256, 0, stream>>>(accw, lw, out, K);
}

// Round 10
// 172.715 us; speedup vs baseline: 1.0209x; 1.0209x over previous
//
#include <hip/hip_runtime.h>
#include <math.h>

#define B 4
#define S 2048
#define E 1024
#define H 64
#define BS (B*S)
#define LOG2E 1.44269504088896f
#define CINIT (-69.2493662f)   // -48 * log2(e): fixed softmax max in log2 domain

typedef float v4f __attribute__((ext_vector_type(4)));
typedef short v8s __attribute__((ext_vector_type(8)));
typedef unsigned short u16;
typedef u16 u16x8 __attribute__((ext_vector_type(8)));
typedef u16 u16x4 __attribute__((ext_vector_type(4)));

#define MFMA(a,b,c) __builtin_amdgcn_mfma_f32_16x16x32_bf16(a,b,c,0,0,0)

// round-half-up fp32 -> bf16
__device__ inline u16 rh_bf16(float x){ return (u16)((__float_as_uint(x)+0x8000u)>>16); }

// ============================================================
// k0: W[E][H] fp32 -> transposed hi/lo bf16 planes Wt[p][h][e].
// p==0 (Wq) pre-scaled by log2(e) so scores land in log2 domain.
// ============================================================
__global__ __launch_bounds__(256) void wsetup_kernel(
    const float* __restrict__ Wq, const float* __restrict__ Wk,
    const float* __restrict__ Wv,
    u16* __restrict__ Wt_hi, u16* __restrict__ Wt_lo)
{
    __shared__ float wt[64][65];
    const int t  = threadIdx.x;
    const int p  = blockIdx.x >> 4;
    const int e0 = (blockIdx.x & 15) * 64;
    const float* Wsrc = (p==0) ? Wq : (p==1 ? Wk : Wv);
    const float scale = (p==0) ? LOG2E : 1.0f;

    #pragma unroll
    for (int i=0;i<16;i++){
        int e_l = i*4 + (t>>6);
        wt[e_l][t&63] = Wsrc[(size_t)(e0+e_l)*H + (t&63)] * scale;
    }
    __syncthreads();

    const int h = t>>2, e16 = (t&3)*16;
    u16 hi_a[16], lo_a[16];
    #pragma unroll
    for (int j=0;j<16;j++){
        float f = wt[e16+j][h];
        unsigned u = __float_as_uint(f);
        hi_a[j] = (u16)(u>>16);                       // truncation split
        float hif = __uint_as_float(u & 0xFFFF0000u);
        lo_a[j] = rh_bf16(f - hif);                   // residual to bf16
    }
    u16* dh = Wt_hi + (size_t)(p*64+h)*E + e0 + e16;
    u16* dl = Wt_lo + (size_t)(p*64+h)*E + e0 + e16;
    *(u16x8*)dh     = *(u16x8*)&hi_a[0];
    *(u16x8*)(dh+8) = *(u16x8*)&hi_a[8];
    *(u16x8*)dl     = *(u16x8*)&lo_a[0];
    *(u16x8*)(dl+8) = *(u16x8*)&lo_a[8];
}

// ============================================================
// k1: projections via MFMA with hi/lo 3-term products (~fp32 exact).
// block = 256 thr (4 waves) covering 32 rows x 64 h.
//   wave wv: row-half = wv>>1 (16 rows), h-half = wv&1 (2 n-tiles).
// Best-measured structure (164.06 us pipeline). SINGLE change this
// round: the t+1 prefetch is issued AFTER the second __syncthreads
// (not between the barriers), so its loads fly under the MFMA body and
// drain at the NEXT iteration's first barrier, instead of being
// force-drained by the second barrier's vmcnt(0) before any compute.
// v projection (p==2) transposed in-block, written to vt[b][h][s].
// ============================================================
__global__ __launch_bounds__(256, 3) void proj_kernel(
    const float* __restrict__ query, const float* __restrict__ key_,
    const float* __restrict__ value,
    const u16* __restrict__ Wt_hi, const u16* __restrict__ Wt_lo,
    const float* __restrict__ bq, const float* __restrict__ bk,
    const float* __restrict__ bv,
    u16* __restrict__ q_hi, u16* __restrict__ q_lo,
    u16* __restrict__ k_hi, u16* __restrict__ k_lo,
    u16* __restrict__ vt)
{
    __shared__ __align__(16) u16 xh[32][72], xl[32][72];   // x tile hi/lo
    __shared__ __align__(16) u16 wh[64][72], wl[64][72];   // W^T tile hi/lo
    __shared__ __align__(16) u16 vtile[64][40];            // v transpose staging

    const int t  = threadIdx.x;
    const int p  = blockIdx.x >> 8;           // 0..2
    const int r0 = (blockIdx.x & 255) * 32;   // global row base (flat [BS])
    const float* xp = (p==0) ? query : (p==1 ? key_ : value);
    const int wv = t>>6, lane = t&63, m = lane&15, quad = lane>>4;
    const int whalf = wv>>1, nh = wv&1;

    const int srow = t>>3, se8 = (t&7)*8;     // x staging: 8 fp32/thread
    const int swh  = t>>2, seo  = (t&3)*16;   // W staging: 16 u16/thread/plane

    const float* xb  = xp + (size_t)(r0+srow)*E + se8;
    const u16*   shb = Wt_hi + (size_t)(p*64+swh)*E + seo;
    const u16*   slb = Wt_lo + (size_t)(p*64+swh)*E + seo;

    v4f acc[2];
    acc[0] = (v4f){0.f,0.f,0.f,0.f};
    acc[1] = (v4f){0.f,0.f,0.f,0.f};

    // ping-pong register sets
    float4 xA[2], xB[2];
    u16x8  wA[4], wB[4];
    xA[0] = *(const float4*)(xb);
    xA[1] = *(const float4*)(xb+4);
    wA[0] = *(const u16x8*)(shb);   wA[1] = *(const u16x8*)(shb+8);
    wA[2] = *(const u16x8*)(slb);   wA[3] = *(const u16x8*)(slb+8);

#define PROJ_ITER(EC, XC, WC, XN, WN, PREF)                                    \
    {                                                                          \
        __syncthreads();                                                       \
        float fv[8] = {XC[0].x,XC[0].y,XC[0].z,XC[0].w,                        \
                       XC[1].x,XC[1].y,XC[1].z,XC[1].w};                       \
        u16 ha[8], la[8];                                                      \
        _Pragma("unroll")                                                      \
        for (int j=0;j<8;j++){                                                 \
            unsigned u = __float_as_uint(fv[j]);                               \
            ha[j] = (u16)(u>>16);                                              \
            la[j] = rh_bf16(fv[j] - __uint_as_float(u & 0xFFFF0000u));         \
        }                                                                      \
        *(u16x8*)&xh[srow][se8] = *(u16x8*)&ha[0];                             \
        *(u16x8*)&xl[srow][se8] = *(u16x8*)&la[0];                             \
        *(u16x8*)&wh[swh][seo]   = WC[0];                                      \
        *(u16x8*)&wh[swh][seo+8] = WC[1];                                      \
        *(u16x8*)&wl[swh][seo]   = WC[2];                                      \
        *(u16x8*)&wl[swh][seo+8] = WC[3];                                      \
        __syncthreads();                                                       \
        /* prefetch AFTER the drain barrier: overlaps the MFMA body,   */      \
        /* drained by the NEXT iteration's first __syncthreads.        */      \
        if (PREF){                                                             \
            const float* xn = xb + ((EC)+1)*64;                                \
            XN[0] = *(const float4*)(xn);                                      \
            XN[1] = *(const float4*)(xn+4);                                    \
            const u16* shn = shb + ((EC)+1)*64;                                \
            const u16* sln = slb + ((EC)+1)*64;                                \
            WN[0]=*(const u16x8*)(shn); WN[1]=*(const u16x8*)(shn+8);          \
            WN[2]=*(const u16x8*)(sln); WN[3]=*(const u16x8*)(sln+8);          \
        }                                                                      \
        v8s ah0 = *(v8s*)&xh[whalf*16+m][quad*8];                              \
        v8s ah1 = *(v8s*)&xh[whalf*16+m][32+quad*8];                           \
        v8s al0 = *(v8s*)&xl[whalf*16+m][quad*8];                              \
        v8s al1 = *(v8s*)&xl[whalf*16+m][32+quad*8];                           \
        _Pragma("unroll")                                                      \
        for (int i=0;i<2;i++){                                                 \
            const int nt = nh*2+i;                                             \
            v8s bh0 = *(v8s*)&wh[nt*16+m][quad*8];                             \
            v8s bh1 = *(v8s*)&wh[nt*16+m][32+quad*8];                          \
            v8s bl0 = *(v8s*)&wl[nt*16+m][quad*8];                             \
            v8s bl1 = *(v8s*)&wl[nt*16+m][32+quad*8];                          \
            v4f d = acc[i];                                                    \
            d = MFMA(ah0,bh0,d); d = MFMA(ah1,bh1,d);                          \
            d = MFMA(al0,bh0,d); d = MFMA(al1,bh1,d);                          \
            d = MFMA(ah0,bl0,d); d = MFMA(ah1,bl1,d);                          \
            acc[i] = d;                                                        \
        }                                                                      \
    }

    for (int ec2=0; ec2<16; ec2+=2){
        PROJ_ITER(ec2,   xA, wA, xB, wB, true)
        PROJ_ITER(ec2+1, xB, wB, xA, wA, (ec2<14))
    }
#undef PROJ_ITER

    // ---- epilogue ----
    const float* bp = (p==0) ? bq : (p==1 ? bk : bv);
    if (p<2){
        const float bscale = (p==0) ? LOG2E : 1.0f;
        u16* dh = (p==0) ? q_hi : k_hi;
        u16* dl = (p==0) ? q_lo : k_lo;
        #pragma unroll
        for (int i=0;i<2;i++){
            const int hl = (nh*2+i)*16+m;
            const float bb = bp[hl]*bscale;
            #pragma unroll
            for (int r=0;r<4;r++){
                const int gr = r0 + whalf*16 + quad*4 + r;  // D: row = quad*4+reg
                const float val = acc[i][r] + bb;
                unsigned u = __float_as_uint(val);
                u16 hi = (u16)(u>>16);
                float hif = __uint_as_float(u & 0xFFFF0000u);
                u16 lo = rh_bf16(val - hif);
                dh[(size_t)gr*H + hl] = hi;
                dl[(size_t)gr*H + hl] = lo;
            }
        }
    } else {
        // v: bf16 into LDS transposed, then coalesced store to vt[b][h][s]
        const int rlb = whalf*16 + quad*4;
        #pragma unroll
        for (int i=0;i<2;i++){
            const int hl = (nh*2+i)*16+m;
            const float bb = bp[hl];
            u16 vv[4];
            #pragma unroll
            for (int r=0;r<4;r++) vv[r] = rh_bf16(acc[i][r] + bb);
            *(u16x4*)&vtile[hl][rlb] = *(u16x4*)&vv[0];
        }
        __syncthreads();
        const int h = t>>2, so = (t&3)*8;
        const int bidx = r0 >> 11, s0l = r0 & (S-1);
        u16* dst = vt + ((size_t)(bidx*H + h))*S + s0l + so;
        *(u16x8*)dst = *(const u16x8*)&vtile[h][so];
    }
}

// ============================================================
// k3: flash attention, fixed-max softmax (log2 domain), split-K.
// block = 256 thr (4 waves x 16 q-rows = 64 q-rows), TK=32/iter.
// Same single change as proj: prefetch issued AFTER the second
// __syncthreads so the loads overlap QK^T/softmax/PV and drain at the
// next iteration's first barrier.
// ============================================================
__global__ __launch_bounds__(256, 4) void attn_kernel(
    const u16* __restrict__ qh_g, const u16* __restrict__ ql_g,
    const u16* __restrict__ kh_g, const u16* __restrict__ kl_g,
    const u16* __restrict__ vt_g,
    float* __restrict__ accw, float* __restrict__ lw, int ksplit)
{
    __shared__ __align__(16) u16 khe[2][16][72];   // [jj&1][jj>>1][h]
    __shared__ __align__(16) u16 kle[2][16][72];
    __shared__ __align__(16) u16 vtl[64][40];      // [h][jj]
    __shared__ __align__(16) u16 pl[4][16][40];    // per-wave P [row][jj]

    const int t = threadIdx.x;
    const int wv = t>>6, lane = t&63, m = lane&15, quad = lane>>4;
    const int bid = blockIdx.x;
    const int qb = bid / ksplit, chunk = bid % ksplit;
    const int b = qb >> 5, s0 = (qb & 31)*64;
    const int ck = S / ksplit;
    const int j0base = chunk * ck;
    const int iters = ck / 32;

    // persistent q fragments (hi c0/c1, lo c0/c1)
    const u16* qr = qh_g + (size_t)(b*S + s0 + wv*16 + m)*H + quad*8;
    const u16* qrl = ql_g + (size_t)(b*S + s0 + wv*16 + m)*H + quad*8;
    const v8s qh0 = *(const v8s*)(qr),  qh1 = *(const v8s*)(qr+32);
    const v8s ql0 = *(const v8s*)(qrl), ql1 = *(const v8s*)(qrl+32);

    v4f oacc[4];
    #pragma unroll
    for (int nt=0;nt<4;nt++) oacc[nt] = (v4f){0.f,0.f,0.f,0.f};
    float lp[4] = {0.f,0.f,0.f,0.f};
    const v4f cinit = (v4f){CINIT,CINIT,CINIT,CINIT};

    // staging coords
    const int sj = t>>3, sh8 = (t&7)*8;   // K tiles: 32 rows x 64 h
    const u16* khs = kh_g + (size_t)(b*S + j0base + sj)*H + sh8;
    const u16* kls = kl_g + (size_t)(b*S + j0base + sj)*H + sh8;
    u16* khd = &khe[sj&1][sj>>1][sh8];
    u16* kld = &kle[sj&1][sj>>1][sh8];
    const int vh = t>>2, vj8 = (t&3)*8;   // vt tile: 64 h x 32 jj
    const u16* vts = vt_g + (size_t)(b*H + vh)*S + j0base + vj8;
    u16* vtd = &vtl[vh][vj8];

    // ping-pong staging registers
    u16x8 khA, klA, vtA, khB, klB, vtB;
    khA = *(const u16x8*)khs;
    klA = *(const u16x8*)kls;
    vtA = *(const u16x8*)vts;

#define ATTN_ITER(IT, KHC, KLC, VTC, KHN, KLN, VTN, PREF)                      \
    {                                                                          \
        __syncthreads();                                                       \
        *(u16x8*)khd = KHC; *(u16x8*)kld = KLC; *(u16x8*)vtd = VTC;            \
        __syncthreads();                                                       \
        /* prefetch AFTER the drain barrier (overlaps QK^T/softmax/PV) */      \
        if (PREF){                                                             \
            KHN = *(const u16x8*)(khs + (size_t)((IT)+1)*32*H);                \
            KLN = *(const u16x8*)(kls + (size_t)((IT)+1)*32*H);                \
            VTN = *(const u16x8*)(vts + ((IT)+1)*32);                          \
        }                                                                      \
        /* QK^T: 2 D-tiles x 6 MFMAs (3-term hi/lo), C-init = -m_fix */        \
        v4f sc[2];                                                             \
        _Pragma("unroll")                                                      \
        for (int jt=0;jt<2;jt++){                                              \
            const u16* kr  = &khe[jt][m][quad*8];                              \
            const u16* krl = &kle[jt][m][quad*8];                              \
            v8s b0 = *(const v8s*)kr,  b1 = *(const v8s*)(kr+32);              \
            v8s c0 = *(const v8s*)krl, c1 = *(const v8s*)(krl+32);             \
            v4f d = cinit;                                                     \
            d = MFMA(qh0,b0,d); d = MFMA(qh1,b1,d);                            \
            d = MFMA(ql0,b0,d); d = MFMA(ql1,b1,d);                            \
            d = MFMA(qh0,c0,d); d = MFMA(qh1,c1,d);                            \
            sc[jt] = d;                                                        \
        }                                                                      \
        /* P = exp2(s'), accumulate l, pack bf16 pairs to wave-local LDS */    \
        _Pragma("unroll")                                                      \
        for (int r=0;r<4;r++){                                                 \
            float p0 = exp2f(sc[0][r]);   /* key j0 + 2m   */                  \
            float p1 = exp2f(sc[1][r]);   /* key j0 + 2m+1 */                  \
            lp[r] += p0 + p1;                                                  \
            unsigned pk = ((__float_as_uint(p0)+0x8000u)>>16)                  \
                        | ((__float_as_uint(p1)+0x8000u) & 0xFFFF0000u);       \
            *(unsigned*)&pl[wv][quad*4+r][2*m] = pk;                           \
        }                                                                      \
        /* no barrier: pl[wv] is wave-private, DS ops are in program order */  \
        v8s pa = *(const v8s*)&pl[wv][m][quad*8];                              \
        _Pragma("unroll")                                                      \
        for (int nt=0;nt<4;nt++){                                              \
            v8s vb = *(const v8s*)&vtl[nt*16+m][quad*8];                       \
            oacc[nt] = MFMA(pa, vb, oacc[nt]);                                 \
        }                                                                      \
    }

    for (int it=0; it<iters; it+=2){   // iters = 64/ksplit, always even
        ATTN_ITER(it,   khA,klA,vtA, khB,klB,vtB, true)
        ATTN_ITER(it+1, khB,klB,vtB, khA,klA,vtA, (it+2<iters))
    }
#undef ATTN_ITER

    // ---- epilogue: reduce l across 16 cols, write partials ----
    #pragma unroll
    for (int r=0;r<4;r++){
        float v = lp[r];
        v += __shfl_xor(v,1); v += __shfl_xor(v,2);
        v += __shfl_xor(v,4); v += __shfl_xor(v,8);
        lp[r] = v;
    }
    const int growb = b*S + s0 + wv*16;
    if (m==0){
        float4 lv; lv.x=lp[0]; lv.y=lp[1]; lv.z=lp[2]; lv.w=lp[3];
        *(float4*)(lw + (size_t)chunk*BS + growb + quad*4) = lv;
    }
    float* ab = accw + ((size_t)chunk*BS + growb)*H;
    #pragma unroll
    for (int nt=0;nt<4;nt++){
        #pragma unroll
        for (int r=0;r<4;r++)
            ab[(size_t)(quad*4+r)*H + nt*16 + m] = oacc[nt][r];
    }
}

// ============================================================
// k4: merge split-K partials: out = sum_c acc / sum_c l
// ============================================================
__global__ __launch_bounds__(256) void merge_kernel(
    const float* __restrict__ accw, const float* __restrict__ lw,
    float* __restrict__ out, int ksplit)
{
    const int idx = blockIdx.x*256 + threadIdx.x;
    const int row = idx >> 4, h4 = (idx & 15)*4;
    float4 a = {0.f,0.f,0.f,0.f};
    float ls = 0.f;
    for (int c=0;c<ksplit;c++){
        const float4 t4 = *(const float4*)(accw + ((size_t)c*BS + row)*H + h4);
        a.x+=t4.x; a.y+=t4.y; a.z+=t4.z; a.w+=t4.w;
        ls += lw[(size_t)c*BS + row];
    }
    const float inv = __builtin_amdgcn_rcpf(ls);
    float4 o; o.x=a.x*inv; o.y=a.y*inv; o.z=a.z*inv; o.w=a.w*inv;
    *(float4*)(out + (size_t)row*H + h4) = o;
}

// ============================================================
extern "C" void kernel_launch(void* const* d_in, const int* in_sizes, int n_in,
                              void* d_out, int out_size, void* d_ws, size_t ws_size,
                              hipStream_t stream) {
    const float* query = (const float*)d_in[0];
    const float* key_  = (const float*)d_in[1];
    const float* value = (const float*)d_in[2];
    const float* Wq    = (const float*)d_in[3];
    const float* bq    = (const float*)d_in[4];
    const float* Wk    = (const float*)d_in[5];
    const float* bk    = (const float*)d_in[6];
    const float* Wv    = (const float*)d_in[7];
    const float* bv    = (const float*)d_in[8];
    float* out = (float*)d_out;

    char* base = (char*)d_ws;
    size_t off = 0;
    u16* Wt_hi = (u16*)(base + off); off += (size_t)3*64*E*2;
    u16* Wt_lo = (u16*)(base + off); off += (size_t)3*64*E*2;
    u16* q_hi  = (u16*)(base + off); off += (size_t)BS*H*2;
    u16* q_lo  = (u16*)(base + off); off += (size_t)BS*H*2;
    u16* k_hi  = (u16*)(base + off); off += (size_t)BS*H*2;
    u16* k_lo  = (u16*)(base + off); off += (size_t)BS*H*2;
    u16* vt    = (u16*)(base + off); off += (size_t)BS*H*2;
    const size_t fixed = off;
    const size_t CH = (size_t)BS*H*4 + (size_t)BS*4;  // acc + l per chunk

    int K = 1;
    if      (ws_size >= fixed + 8*CH) K = 8;
    else if (ws_size >= fixed + 4*CH) K = 4;
    else if (ws_size >= fixed + 2*CH) K = 2;

    float* lw   = (float*)(base + fixed);
    float* accw = (float*)(base + fixed + (size_t)K*BS*4);

    wsetup_kernel<<<48, 256, 0, stream>>>(Wq, Wk, Wv, Wt_hi, Wt_lo);
    proj_kernel<<<768, 256, 0, stream>>>(query, key_, value, Wt_hi, Wt_lo,
                                         bq, bk, bv, q_hi, q_lo, k_hi, k_lo, vt);
    attn_kernel<<<128*K, 256, 0, stream>>>(q_hi, q_lo, k_hi, k_lo, vt, accw, lw, K);
    merge_kernel<<<512, 256, 0, stream>>>(accw, lw, out, K);
}

// Round 11
// 162.645 us; speedup vs baseline: 1.0841x; 1.0619x over previous
//
#include <hip/hip_runtime.h>
#include <math.h>

#define B 4
#define S 2048
#define E 1024
#define H 64
#define BS (B*S)
#define LOG2E 1.44269504088896f
#define CINIT (-69.2493662f)   // -48 * log2(e): fixed softmax max in log2 domain

typedef float v4f __attribute__((ext_vector_type(4)));
typedef short v8s __attribute__((ext_vector_type(8)));
typedef unsigned short u16;
typedef u16 u16x8 __attribute__((ext_vector_type(8)));
typedef u16 u16x4 __attribute__((ext_vector_type(4)));

#define MFMA(a,b,c) __builtin_amdgcn_mfma_f32_16x16x32_bf16(a,b,c,0,0,0)

// round-half-up fp32 -> bf16
__device__ inline u16 rh_bf16(float x){ return (u16)((__float_as_uint(x)+0x8000u)>>16); }

// ============================================================
// k0: W[E][H] fp32 -> transposed hi/lo bf16 planes Wt[p][h][e].
// p==0 (Wq) pre-scaled by log2(e) so scores land in log2 domain.
// ============================================================
__global__ __launch_bounds__(256) void wsetup_kernel(
    const float* __restrict__ Wq, const float* __restrict__ Wk,
    const float* __restrict__ Wv,
    u16* __restrict__ Wt_hi, u16* __restrict__ Wt_lo)
{
    __shared__ float wt[64][65];
    const int t  = threadIdx.x;
    const int p  = blockIdx.x >> 4;
    const int e0 = (blockIdx.x & 15) * 64;
    const float* Wsrc = (p==0) ? Wq : (p==1 ? Wk : Wv);
    const float scale = (p==0) ? LOG2E : 1.0f;

    #pragma unroll
    for (int i=0;i<16;i++){
        int e_l = i*4 + (t>>6);
        wt[e_l][t&63] = Wsrc[(size_t)(e0+e_l)*H + (t&63)] * scale;
    }
    __syncthreads();

    const int h = t>>2, e16 = (t&3)*16;
    u16 hi_a[16], lo_a[16];
    #pragma unroll
    for (int j=0;j<16;j++){
        float f = wt[e16+j][h];
        unsigned u = __float_as_uint(f);
        hi_a[j] = (u16)(u>>16);                       // truncation split
        float hif = __uint_as_float(u & 0xFFFF0000u);
        lo_a[j] = rh_bf16(f - hif);                   // residual to bf16
    }
    u16* dh = Wt_hi + (size_t)(p*64+h)*E + e0 + e16;
    u16* dl = Wt_lo + (size_t)(p*64+h)*E + e0 + e16;
    *(u16x8*)dh     = *(u16x8*)&hi_a[0];
    *(u16x8*)(dh+8) = *(u16x8*)&hi_a[8];
    *(u16x8*)dl     = *(u16x8*)&lo_a[0];
    *(u16x8*)(dl+8) = *(u16x8*)&lo_a[8];
}

// ============================================================
// k1: projections via MFMA with hi/lo 3-term products (~fp32 exact).
// block = 256 thr (4 waves) covering 32 rows x 64 h.
//   wave wv: row-half = wv>>1 (16 rows), h-half = wv&1 (2 n-tiles).
// __launch_bounds__(256,3): min 3 waves/EU -> VGPR headroom for the
// staging pipeline (best-measured configuration of this session).
// T14 ping-pong prefetch of next x/W chunk into registers.
// v projection (p==2) transposed in-block, written to vt[b][h][s].
// ============================================================
__global__ __launch_bounds__(256, 3) void proj_kernel(
    const float* __restrict__ query, const float* __restrict__ key_,
    const float* __restrict__ value,
    const u16* __restrict__ Wt_hi, const u16* __restrict__ Wt_lo,
    const float* __restrict__ bq, const float* __restrict__ bk,
    const float* __restrict__ bv,
    u16* __restrict__ q_hi, u16* __restrict__ q_lo,
    u16* __restrict__ k_hi, u16* __restrict__ k_lo,
    u16* __restrict__ vt)
{
    __shared__ __align__(16) u16 xh[32][72], xl[32][72];   // x tile hi/lo
    __shared__ __align__(16) u16 wh[64][72], wl[64][72];   // W^T tile hi/lo
    __shared__ __align__(16) u16 vtile[64][40];            // v transpose staging

    const int t  = threadIdx.x;
    const int p  = blockIdx.x >> 8;           // 0..2
    const int r0 = (blockIdx.x & 255) * 32;   // global row base (flat [BS])
    const float* xp = (p==0) ? query : (p==1 ? key_ : value);
    const int wv = t>>6, lane = t&63, m = lane&15, quad = lane>>4;
    const int whalf = wv>>1, nh = wv&1;

    const int srow = t>>3, se8 = (t&7)*8;     // x staging: 8 fp32/thread
    const int swh  = t>>2, seo  = (t&3)*16;   // W staging: 16 u16/thread/plane

    const float* xb  = xp + (size_t)(r0+srow)*E + se8;
    const u16*   shb = Wt_hi + (size_t)(p*64+swh)*E + seo;
    const u16*   slb = Wt_lo + (size_t)(p*64+swh)*E + seo;

    v4f acc[2];
    acc[0] = (v4f){0.f,0.f,0.f,0.f};
    acc[1] = (v4f){0.f,0.f,0.f,0.f};

    // ping-pong register sets (T14)
    float4 xA[2], xB[2];
    u16x8  wA[4], wB[4];
    xA[0] = *(const float4*)(xb);
    xA[1] = *(const float4*)(xb+4);
    wA[0] = *(const u16x8*)(shb);   wA[1] = *(const u16x8*)(shb+8);
    wA[2] = *(const u16x8*)(slb);   wA[3] = *(const u16x8*)(slb+8);

#define PROJ_ITER(EC, XC, WC, XN, WN, PREF)                                    \
    {                                                                          \
        __syncthreads();                                                       \
        float fv[8] = {XC[0].x,XC[0].y,XC[0].z,XC[0].w,                        \
                       XC[1].x,XC[1].y,XC[1].z,XC[1].w};                       \
        u16 ha[8], la[8];                                                      \
        _Pragma("unroll")                                                      \
        for (int j=0;j<8;j++){                                                 \
            unsigned u = __float_as_uint(fv[j]);                               \
            ha[j] = (u16)(u>>16);                                              \
            la[j] = rh_bf16(fv[j] - __uint_as_float(u & 0xFFFF0000u));         \
        }                                                                      \
        *(u16x8*)&xh[srow][se8] = *(u16x8*)&ha[0];                             \
        *(u16x8*)&xl[srow][se8] = *(u16x8*)&la[0];                             \
        *(u16x8*)&wh[swh][seo]   = WC[0];                                      \
        *(u16x8*)&wh[swh][seo+8] = WC[1];                                      \
        *(u16x8*)&wl[swh][seo]   = WC[2];                                      \
        *(u16x8*)&wl[swh][seo+8] = WC[3];                                      \
        if (PREF){                                                             \
            const float* xn = xb + ((EC)+1)*64;                                \
            XN[0] = *(const float4*)(xn);                                      \
            XN[1] = *(const float4*)(xn+4);                                    \
            const u16* shn = shb + ((EC)+1)*64;                                \
            const u16* sln = slb + ((EC)+1)*64;                                \
            WN[0]=*(const u16x8*)(shn); WN[1]=*(const u16x8*)(shn+8);          \
            WN[2]=*(const u16x8*)(sln); WN[3]=*(const u16x8*)(sln+8);          \
        }                                                                      \
        __syncthreads();                                                       \
        v8s ah0 = *(v8s*)&xh[whalf*16+m][quad*8];                              \
        v8s ah1 = *(v8s*)&xh[whalf*16+m][32+quad*8];                           \
        v8s al0 = *(v8s*)&xl[whalf*16+m][quad*8];                              \
        v8s al1 = *(v8s*)&xl[whalf*16+m][32+quad*8];                           \
        _Pragma("unroll")                                                      \
        for (int i=0;i<2;i++){                                                 \
            const int nt = nh*2+i;                                             \
            v8s bh0 = *(v8s*)&wh[nt*16+m][quad*8];                             \
            v8s bh1 = *(v8s*)&wh[nt*16+m][32+quad*8];                          \
            v8s bl0 = *(v8s*)&wl[nt*16+m][quad*8];                             \
            v8s bl1 = *(v8s*)&wl[nt*16+m][32+quad*8];                          \
            v4f d = acc[i];                                                    \
            d = MFMA(ah0,bh0,d); d = MFMA(ah1,bh1,d);                          \
            d = MFMA(al0,bh0,d); d = MFMA(al1,bh1,d);                          \
            d = MFMA(ah0,bl0,d); d = MFMA(ah1,bl1,d);                          \
            acc[i] = d;                                                        \
        }                                                                      \
    }

    for (int ec2=0; ec2<16; ec2+=2){
        PROJ_ITER(ec2,   xA, wA, xB, wB, true)
        PROJ_ITER(ec2+1, xB, wB, xA, wA, (ec2<14))
    }
#undef PROJ_ITER

    // ---- epilogue ----
    const float* bp = (p==0) ? bq : (p==1 ? bk : bv);
    if (p<2){
        const float bscale = (p==0) ? LOG2E : 1.0f;
        u16* dh = (p==0) ? q_hi : k_hi;
        u16* dl = (p==0) ? q_lo : k_lo;
        #pragma unroll
        for (int i=0;i<2;i++){
            const int hl = (nh*2+i)*16+m;
            const float bb = bp[hl]*bscale;
            #pragma unroll
            for (int r=0;r<4;r++){
                const int gr = r0 + whalf*16 + quad*4 + r;  // D: row = quad*4+reg
                const float val = acc[i][r] + bb;
                unsigned u = __float_as_uint(val);
                u16 hi = (u16)(u>>16);
                float hif = __uint_as_float(u & 0xFFFF0000u);
                u16 lo = rh_bf16(val - hif);
                dh[(size_t)gr*H + hl] = hi;
                dl[(size_t)gr*H + hl] = lo;
            }
        }
    } else {
        // v: bf16 into LDS transposed, then coalesced store to vt[b][h][s]
        const int rlb = whalf*16 + quad*4;
        #pragma unroll
        for (int i=0;i<2;i++){
            const int hl = (nh*2+i)*16+m;
            const float bb = bp[hl];
            u16 vv[4];
            #pragma unroll
            for (int r=0;r<4;r++) vv[r] = rh_bf16(acc[i][r] + bb);
            *(u16x4*)&vtile[hl][rlb] = *(u16x4*)&vv[0];
        }
        __syncthreads();
        const int h = t>>2, so = (t&3)*8;
        const int bidx = r0 >> 11, s0l = r0 & (S-1);
        u16* dst = vt + ((size_t)(bidx*H + h))*S + s0l + so;
        *(u16x8*)dst = *(const u16x8*)&vtile[h][so];
    }
}

// ============================================================
// k3: flash attention, fixed-max softmax (log2 domain), split-K.
// block = 256 thr (4 waves x 16 q-rows = 64 q-rows), TK=32/iter.
// __launch_bounds__(256,4): VGPR cap 128.
// T14 ping-pong: next tile's K-hi/K-lo/Vt loads issued into the other
// register set before the compute barrier. pl[wv] is wave-private,
// so no barrier between P-write and PV.
// ============================================================
__global__ __launch_bounds__(256, 4) void attn_kernel(
    const u16* __restrict__ qh_g, const u16* __restrict__ ql_g,
    const u16* __restrict__ kh_g, const u16* __restrict__ kl_g,
    const u16* __restrict__ vt_g,
    float* __restrict__ accw, float* __restrict__ lw, int ksplit)
{
    __shared__ __align__(16) u16 khe[2][16][72];   // [jj&1][jj>>1][h]
    __shared__ __align__(16) u16 kle[2][16][72];
    __shared__ __align__(16) u16 vtl[64][40];      // [h][jj]
    __shared__ __align__(16) u16 pl[4][16][40];    // per-wave P [row][jj]

    const int t = threadIdx.x;
    const int wv = t>>6, lane = t&63, m = lane&15, quad = lane>>4;
    const int bid = blockIdx.x;
    const int qb = bid / ksplit, chunk = bid % ksplit;
    const int b = qb >> 5, s0 = (qb & 31)*64;
    const int ck = S / ksplit;
    const int j0base = chunk * ck;
    const int iters = ck / 32;

    // persistent q fragments (hi c0/c1, lo c0/c1)
    const u16* qr = qh_g + (size_t)(b*S + s0 + wv*16 + m)*H + quad*8;
    const u16* qrl = ql_g + (size_t)(b*S + s0 + wv*16 + m)*H + quad*8;
    const v8s qh0 = *(const v8s*)(qr),  qh1 = *(const v8s*)(qr+32);
    const v8s ql0 = *(const v8s*)(qrl), ql1 = *(const v8s*)(qrl+32);

    v4f oacc[4];
    #pragma unroll
    for (int nt=0;nt<4;nt++) oacc[nt] = (v4f){0.f,0.f,0.f,0.f};
    float lp[4] = {0.f,0.f,0.f,0.f};
    const v4f cinit = (v4f){CINIT,CINIT,CINIT,CINIT};

    // staging coords
    const int sj = t>>3, sh8 = (t&7)*8;   // K tiles: 32 rows x 64 h
    const u16* khs = kh_g + (size_t)(b*S + j0base + sj)*H + sh8;
    const u16* kls = kl_g + (size_t)(b*S + j0base + sj)*H + sh8;
    u16* khd = &khe[sj&1][sj>>1][sh8];
    u16* kld = &kle[sj&1][sj>>1][sh8];
    const int vh = t>>2, vj8 = (t&3)*8;   // vt tile: 64 h x 32 jj
    const u16* vts = vt_g + (size_t)(b*H + vh)*S + j0base + vj8;
    u16* vtd = &vtl[vh][vj8];

    // ping-pong staging registers (T14)
    u16x8 khA, klA, vtA, khB, klB, vtB;
    khA = *(const u16x8*)khs;
    klA = *(const u16x8*)kls;
    vtA = *(const u16x8*)vts;

#define ATTN_ITER(IT, KHC, KLC, VTC, KHN, KLN, VTN, PREF)                      \
    {                                                                          \
        __syncthreads();                                                       \
        *(u16x8*)khd = KHC; *(u16x8*)kld = KLC; *(u16x8*)vtd = VTC;            \
        if (PREF){                                                             \
            KHN = *(const u16x8*)(khs + (size_t)((IT)+1)*32*H);                \
            KLN = *(const u16x8*)(kls + (size_t)((IT)+1)*32*H);                \
            VTN = *(const u16x8*)(vts + ((IT)+1)*32);                          \
        }                                                                      \
        __syncthreads();                                                       \
        /* QK^T: 2 D-tiles x 6 MFMAs (3-term hi/lo), C-init = -m_fix */        \
        v4f sc[2];                                                             \
        _Pragma("unroll")                                                      \
        for (int jt=0;jt<2;jt++){                                              \
            const u16* kr  = &khe[jt][m][quad*8];                              \
            const u16* krl = &kle[jt][m][quad*8];                              \
            v8s b0 = *(const v8s*)kr,  b1 = *(const v8s*)(kr+32);              \
            v8s c0 = *(const v8s*)krl, c1 = *(const v8s*)(krl+32);             \
            v4f d = cinit;                                                     \
            d = MFMA(qh0,b0,d); d = MFMA(qh1,b1,d);                            \
            d = MFMA(ql0,b0,d); d = MFMA(ql1,b1,d);                            \
            d = MFMA(qh0,c0,d); d = MFMA(qh1,c1,d);                            \
            sc[jt] = d;                                                        \
        }                                                                      \
        /* P = exp2(s'), accumulate l, pack bf16 pairs to wave-local LDS */    \
        _Pragma("unroll")                                                      \
        for (int r=0;r<4;r++){                                                 \
            float p0 = exp2f(sc[0][r]);   /* key j0 + 2m   */                  \
            float p1 = exp2f(sc[1][r]);   /* key j0 + 2m+1 */                  \
            lp[r] += p0 + p1;                                                  \
            unsigned pk = ((__float_as_uint(p0)+0x8000u)>>16)                  \
                        | ((__float_as_uint(p1)+0x8000u) & 0xFFFF0000u);       \
            *(unsigned*)&pl[wv][quad*4+r][2*m] = pk;                           \
        }                                                                      \
        /* no barrier: pl[wv] is wave-private, DS ops are in program order */  \
        v8s pa = *(const v8s*)&pl[wv][m][quad*8];                              \
        _Pragma("unroll")                                                      \
        for (int nt=0;nt<4;nt++){                                              \
            v8s vb = *(const v8s*)&vtl[nt*16+m][quad*8];                       \
            oacc[nt] = MFMA(pa, vb, oacc[nt]);                                 \
        }                                                                      \
    }

    for (int it=0; it<iters; it+=2){   // iters = 64/ksplit, always even
        ATTN_ITER(it,   khA,klA,vtA, khB,klB,vtB, true)
        ATTN_ITER(it+1, khB,klB,vtB, khA,klA,vtA, (it+2<iters))
    }
#undef ATTN_ITER

    // ---- epilogue: reduce l across 16 cols, write partials ----
    #pragma unroll
    for (int r=0;r<4;r++){
        float v = lp[r];
        v += __shfl_xor(v,1); v += __shfl_xor(v,2);
        v += __shfl_xor(v,4); v += __shfl_xor(v,8);
        lp[r] = v;
    }
    const int growb = b*S + s0 + wv*16;
    if (m==0){
        float4 lv; lv.x=lp[0]; lv.y=lp[1]; lv.z=lp[2]; lv.w=lp[3];
        *(float4*)(lw + (size_t)chunk*BS + growb + quad*4) = lv;
    }
    float* ab = accw + ((size_t)chunk*BS + growb)*H;
    #pragma unroll
    for (int nt=0;nt<4;nt++){
        #pragma unroll
        for (int r=0;r<4;r++)
            ab[(size_t)(quad*4+r)*H + nt*16 + m] = oacc[nt][r];
    }
}

// ============================================================
// k4: merge split-K partials: out = sum_c acc / sum_c l
// ============================================================
__global__ __launch_bounds__(256) void merge_kernel(
    const float* __restrict__ accw, const float* __restrict__ lw,
    float* __restrict__ out, int ksplit)
{
    const int idx = blockIdx.x*256 + threadIdx.x;
    const int row = idx >> 4, h4 = (idx & 15)*4;
    float4 a = {0.f,0.f,0.f,0.f};
    float ls = 0.f;
    for (int c=0;c<ksplit;c++){
        const float4 t4 = *(const float4*)(accw + ((size_t)c*BS + row)*H + h4);
        a.x+=t4.x; a.y+=t4.y; a.z+=t4.z; a.w+=t4.w;
        ls += lw[(size_t)c*BS + row];
    }
    const float inv = __builtin_amdgcn_rcpf(ls);
    float4 o; o.x=a.x*inv; o.y=a.y*inv; o.z=a.z*inv; o.w=a.w*inv;
    *(float4*)(out + (size_t)row*H + h4) = o;
}

// ============================================================
extern "C" void kernel_launch(void* const* d_in, const int* in_sizes, int n_in,
                              void* d_out, int out_size, void* d_ws, size_t ws_size,
                              hipStream_t stream) {
    const float* query = (const float*)d_in[0];
    const float* key_  = (const float*)d_in[1];
    const float* value = (const float*)d_in[2];
    const float* Wq    = (const float*)d_in[3];
    const float* bq    = (const float*)d_in[4];
    const float* Wk    = (const float*)d_in[5];
    const float* bk    = (const float*)d_in[6];
    const float* Wv    = (const float*)d_in[7];
    const float* bv    = (const float*)d_in[8];
    float* out = (float*)d_out;

    char* base = (char*)d_ws;
    size_t off = 0;
    u16* Wt_hi = (u16*)(base + off); off += (size_t)3*64*E*2;
    u16* Wt_lo = (u16*)(base + off); off += (size_t)3*64*E*2;
    u16* q_hi  = (u16*)(base + off); off += (size_t)BS*H*2;
    u16* q_lo  = (u16*)(base + off); off += (size_t)BS*H*2;
    u16* k_hi  = (u16*)(base + off); off += (size_t)BS*H*2;
    u16* k_lo  = (u16*)(base + off); off += (size_t)BS*H*2;
    u16* vt    = (u16*)(base + off); off += (size_t)BS*H*2;
    const size_t fixed = off;
    const size_t CH = (size_t)BS*H*4 + (size_t)BS*4;  // acc + l per chunk

    int K = 1;
    if      (ws_size >= fixed + 8*CH) K = 8;
    else if (ws_size >= fixed + 4*CH) K = 4;
    else if (ws_size >= fixed + 2*CH) K = 2;

    float* lw   = (float*)(base + fixed);
    float* accw = (float*)(base + fixed + (size_t)K*BS*4);

    wsetup_kernel<<<48, 256, 0, stream>>>(Wq, Wk, Wv, Wt_hi, Wt_lo);
    proj_kernel<<<768, 256, 0, stream>>>(query, key_, value, Wt_hi, Wt_lo,
                                         bq, bk, bv, q_hi, q_lo, k_hi, k_lo, vt);
    attn_kernel<<<128*K, 256, 0, stream>>>(q_hi, q_lo, k_hi, k_lo, vt, accw, lw, K);
    merge_kernel<<<512, 256, 0, stream>>>(accw, lw, out, K);
}